// Round 4
// baseline (293.725 us; speedup 1.0000x reference)
//
#include <hip/hip_runtime.h>

// CoOccurrence: per-pixel 5x5 neighborhood cosine-similarity weighting.
// x: (8, 64, 112, 112) f32, spatial_weight: (25,) f32 -> out: (8, 64, 112, 112) f32.
//
// R4: 256-thread blocks (4 waves). 8x8 pixel tile, 12x12 zero-padded halo in
// LDS (channel stride padded 144->146 for bank spread). Wave w owns the 4x4
// pixel quadrant (w>>1, w&1); lane = (pixel g 0..15, channel-quarter q 0..3).
// Dots reduced with shfl_xor(16/32) butterfly (all lanes get full sum, so
// every lane computes its pixel's 25 weights locally). n2 per halo position
// computed by threads t<144 sweeping the staged tile. Zero-padded halo =>
// OOB taps contribute exactly 0 in phase 2 (reference zero-pad semantics),
// so no validity masks anywhere.

constexpr int Cc = 64, Hc = 112, Wc = 112;
constexpr int HWc = Hc * Wc;
constexpr float EPSc = 1e-8f;
constexpr int TH = 8, TW = 8;
constexpr int WR = 12, HALO = 144;     // 12x12 halo
constexpr int TS = 146;                // padded channel stride (bank spread)
constexpr int CHUNK = 32, NCHUNK = 2;  // channels staged per sweep pass
constexpr int NTX = 14;                // 112/8

__global__ __launch_bounds__(256, 6) void cooc_kernel(
    const float* __restrict__ x, const float* __restrict__ swg,
    float* __restrict__ out)
{
    __shared__ float tile[CHUNK * TS];     // [c][halo pos], 18.7 KB
    __shared__ float n2s[HALO];            // per-halo-pixel sum_c x^2

    const int t = threadIdx.x;
    const int wv = t >> 6;                 // wave 0..3 -> pixel quadrant
    const int l  = t & 63;
    const int g  = l & 15;                 // pixel in quadrant (4x4)
    const int q  = l >> 4;                 // channel quarter within chunk
    const int b = blockIdx.y;
    const int th = blockIdx.x / NTX, twi = blockIdx.x - th * NTX;
    const int h0 = th * TH, w0 = twi * TW;
    const int pr = (wv >> 1) * 4 + (g >> 2);   // pixel row in 8x8 tile
    const int pc = (wv & 1) * 4 + (g & 3);     // pixel col
    const int hp = (pr + 2) * WR + (pc + 2);   // center slot in halo coords

    // Staging slots: wave wv stages 8 channels; lane covers halo positions
    // pos0=l, pos1=l+64, pos2=l+128 (l<16; else harmless dup of pos0).
    const int pos0 = l, pos1 = l + 64;
    const int pos2 = (l < 16) ? l + 128 : l;
    bool i0, i1, i2;
    int go0, go1, go2;
    {
        auto mk = [&](int pos, bool& inb) {
            const int r_ = pos / WR, c_ = pos - r_ * WR;
            const int gh = h0 + r_ - 2, gw = w0 + c_ - 2;
            inb = ((unsigned)gh < (unsigned)Hc) && ((unsigned)gw < (unsigned)Wc);
            return gh * Wc + gw;
        };
        go0 = mk(pos0, i0); go1 = mk(pos1, i1); go2 = mk(pos2, i2);
    }
    const float* xb = x + (size_t)b * Cc * HWc;

    auto stage = [&](int c0) {             // stage channels [c0+wv*8, +8)
        const float* gch = xb + (size_t)(c0 + wv * 8) * HWc;
#pragma unroll
        for (int j = 0; j < 8; ++j) {
            const float* gc = gch + (size_t)j * HWc;
            const float v0 = i0 ? gc[go0] : 0.f;
            const float v1 = i1 ? gc[go1] : 0.f;
            const float v2 = i2 ? gc[go2] : 0.f;
            float* tc = &tile[(wv * 8 + j) * TS];
            tc[pos0] = v0; tc[pos1] = v1; tc[pos2] = v2;
        }
    };

    float dot[25];
#pragma unroll
    for (int k = 0; k < 25; ++k) dot[k] = 0.f;
    float n2acc = 0.f;

    // ---- sweep 1: dots (this lane's 8 channels/chunk) + halo n2 ----
    for (int ch = 0; ch < NCHUNK; ++ch) {
        __syncthreads();
        stage(ch * CHUNK);
        __syncthreads();
        const float* tq = &tile[(q * 8) * TS + hp - 26];
#pragma unroll
        for (int j = 0; j < 8; ++j) {
            const float* p = tq + j * TS;
            const float xv = p[26];
#pragma unroll
            for (int k = 0; k < 25; ++k) {
                dot[k] = fmaf(xv, p[(k / 5) * WR + (k % 5)], dot[k]);
            }
        }
        if (t < HALO) {
            const float* u = &tile[t];
#pragma unroll 8
            for (int c = 0; c < CHUNK; ++c) {
                const float v = u[c * TS];
                n2acc = fmaf(v, v, n2acc);
            }
        }
    }

    if (t < HALO) n2s[t] = n2acc;

    // Butterfly over channel quarters (lanes g, g^16, g^32, g^48): all lanes
    // end with the full-channel dot for their pixel g.
#pragma unroll
    for (int k = 0; k < 25; ++k) {
        dot[k] += __shfl_xor(dot[k], 16);
        dot[k] += __shfl_xor(dot[k], 32);
    }
    __syncthreads();   // n2s visible

    // ---- weights (overwrite dot): sim = dot / max(||x||*||tap||, eps) ----
    const float nx = sqrtf(n2s[hp]);
#pragma unroll
    for (int k = 0; k < 25; ++k) {
        const int off = (k / 5) * WR + (k % 5);
        const float nq = sqrtf(n2s[hp - 26 + off]);
        const float denom = fmaxf(nx * nq, EPSc);
        const float sim = dot[k] / denom;
        dot[k] = (sim + 1.f) * 0.5f * swg[k];
    }

    // ---- sweep 2: out[c] = sum_k wk * tap for this lane's channels ----
    float* ob = out + (size_t)b * Cc * HWc + (h0 + pr) * Wc + (w0 + pc);
    for (int ch = 0; ch < NCHUNK; ++ch) {
        __syncthreads();
        stage(ch * CHUNK);
        __syncthreads();
        const float* tq = &tile[(q * 8) * TS + hp - 26];
#pragma unroll
        for (int j = 0; j < 8; ++j) {
            const float* p = tq + j * TS;
            float acc = 0.f;
#pragma unroll
            for (int k = 0; k < 25; ++k) {
                acc = fmaf(dot[k], p[(k / 5) * WR + (k % 5)], acc);
            }
            ob[(size_t)(ch * CHUNK + q * 8 + j) * HWc] = acc;
        }
    }
}

extern "C" void kernel_launch(void* const* d_in, const int* in_sizes, int n_in,
                              void* d_out, int out_size, void* d_ws, size_t ws_size,
                              hipStream_t stream) {
    const float* x = (const float*)d_in[0];
    const float* sw = (const float*)d_in[1];
    float* out = (float*)d_out;
    cooc_kernel<<<dim3(NTX * NTX, 8), dim3(256), 0, stream>>>(x, sw, out);
}

// Round 5
// 86.838 us; speedup vs baseline: 3.3824x; 3.3824x over previous
//
#include <hip/hip_runtime.h>

// CoOccurrence: per-pixel 5x5 neighborhood cosine-similarity weighting.
// x: (8, 64, 112, 112) f32, spatial_weight: (25,) f32 -> out: (8, 64, 112, 112) f32.
//
// R5 = R4 structure with the spill fixed: launch_bounds(256,2) instead of
// (256,6) (R4's forced 6 waves/EU capped VGPR at ~85 and spilled dot[25] to
// scratch: WRITE_SIZE 25->556 MB, dur 97->294 us). Also: sweep 2 processes
// chunk 1 first straight from the still-resident tile (staged last in sweep
// 1), so only chunk 0 is re-staged (4 -> 3 staging passes).

constexpr int Cc = 64, Hc = 112, Wc = 112;
constexpr int HWc = Hc * Wc;
constexpr float EPSc = 1e-8f;
constexpr int TH = 8, TW = 8;
constexpr int WR = 12, HALO = 144;     // 12x12 halo
constexpr int TS = 146;                // padded channel stride (bank spread)
constexpr int CHUNK = 32;              // channels staged per pass
constexpr int NTX = 14;                // 112/8

__global__ __launch_bounds__(256, 2) void cooc_kernel(
    const float* __restrict__ x, const float* __restrict__ swg,
    float* __restrict__ out)
{
    __shared__ float tile[CHUNK * TS];     // [c][halo pos], 18.7 KB
    __shared__ float n2s[HALO];            // per-halo-pixel sum_c x^2

    const int t = threadIdx.x;
    const int wv = t >> 6;                 // wave 0..3 -> pixel quadrant
    const int l  = t & 63;
    const int g  = l & 15;                 // pixel in quadrant (4x4)
    const int q  = l >> 4;                 // channel quarter within chunk
    const int b = blockIdx.y;
    const int th = blockIdx.x / NTX, twi = blockIdx.x - th * NTX;
    const int h0 = th * TH, w0 = twi * TW;
    const int pr = (wv >> 1) * 4 + (g >> 2);   // pixel row in 8x8 tile
    const int pc = (wv & 1) * 4 + (g & 3);     // pixel col
    const int hp = (pr + 2) * WR + (pc + 2);   // center slot in halo coords

    // Staging slots: wave wv stages 8 channels; lane covers halo positions
    // pos0=l, pos1=l+64, pos2=l+128 (l<16; else harmless dup of pos0).
    const int pos0 = l, pos1 = l + 64;
    const int pos2 = (l < 16) ? l + 128 : l;
    bool i0, i1, i2;
    int go0, go1, go2;
    {
        auto mk = [&](int pos, bool& inb) {
            const int r_ = pos / WR, c_ = pos - r_ * WR;
            const int gh = h0 + r_ - 2, gw = w0 + c_ - 2;
            inb = ((unsigned)gh < (unsigned)Hc) && ((unsigned)gw < (unsigned)Wc);
            return gh * Wc + gw;
        };
        go0 = mk(pos0, i0); go1 = mk(pos1, i1); go2 = mk(pos2, i2);
    }
    const float* xb = x + (size_t)b * Cc * HWc;

    auto stage = [&](int c0) {             // stage channels [c0+wv*8, +8)
        const float* gch = xb + (size_t)(c0 + wv * 8) * HWc;
#pragma unroll
        for (int j = 0; j < 8; ++j) {
            const float* gc = gch + (size_t)j * HWc;
            const float v0 = i0 ? gc[go0] : 0.f;
            const float v1 = i1 ? gc[go1] : 0.f;
            const float v2 = i2 ? gc[go2] : 0.f;
            float* tc = &tile[(wv * 8 + j) * TS];
            tc[pos0] = v0; tc[pos1] = v1; tc[pos2] = v2;
        }
    };

    float dot[25];
#pragma unroll
    for (int k = 0; k < 25; ++k) dot[k] = 0.f;
    float n2acc = 0.f;

    // ---- sweep 1: dots (this lane's 8 channels/chunk) + halo n2 ----
    for (int ch = 0; ch < 2; ++ch) {
        __syncthreads();
        stage(ch * CHUNK);
        __syncthreads();
        const float* tq = &tile[(q * 8) * TS + hp - 26];
#pragma unroll
        for (int j = 0; j < 8; ++j) {
            const float* p = tq + j * TS;
            const float xv = p[26];
#pragma unroll
            for (int k = 0; k < 25; ++k) {
                dot[k] = fmaf(xv, p[(k / 5) * WR + (k % 5)], dot[k]);
            }
        }
        if (t < HALO) {
            const float* u = &tile[t];
#pragma unroll 8
            for (int c = 0; c < CHUNK; ++c) {
                const float v = u[c * TS];
                n2acc = fmaf(v, v, n2acc);
            }
        }
    }

    if (t < HALO) n2s[t] = n2acc;

    // Butterfly over channel quarters (lanes g, g^16, g^32, g^48): all lanes
    // end with the full-channel dot for their pixel g.
#pragma unroll
    for (int k = 0; k < 25; ++k) {
        dot[k] += __shfl_xor(dot[k], 16);
        dot[k] += __shfl_xor(dot[k], 32);
    }
    __syncthreads();   // n2s visible; tile (chunk 1) reads all complete

    // ---- weights (overwrite dot): sim = dot / max(||x||*||tap||, eps) ----
    const float nx = sqrtf(n2s[hp]);
#pragma unroll
    for (int k = 0; k < 25; ++k) {
        const int off = (k / 5) * WR + (k % 5);
        const float nq = sqrtf(n2s[hp - 26 + off]);
        const float denom = fmaxf(nx * nq, EPSc);
        const float sim = dot[k] / denom;
        dot[k] = (sim + 1.f) * 0.5f * swg[k];
    }

    // ---- sweep 2 ----
    float* ob = out + (size_t)b * Cc * HWc + (h0 + pr) * Wc + (w0 + pc);
    // Chunk 1 (channels 32..63) is still resident in LDS from sweep 1.
    {
        const float* tq = &tile[(q * 8) * TS + hp - 26];
#pragma unroll
        for (int j = 0; j < 8; ++j) {
            const float* p = tq + j * TS;
            float acc = 0.f;
#pragma unroll
            for (int k = 0; k < 25; ++k) {
                acc = fmaf(dot[k], p[(k / 5) * WR + (k % 5)], acc);
            }
            ob[(size_t)(CHUNK + q * 8 + j) * HWc] = acc;
        }
    }
    __syncthreads();   // all chunk-1 reads done before restaging
    stage(0);
    __syncthreads();
    {
        const float* tq = &tile[(q * 8) * TS + hp - 26];
#pragma unroll
        for (int j = 0; j < 8; ++j) {
            const float* p = tq + j * TS;
            float acc = 0.f;
#pragma unroll
            for (int k = 0; k < 25; ++k) {
                acc = fmaf(dot[k], p[(k / 5) * WR + (k % 5)], acc);
            }
            ob[(size_t)(q * 8 + j) * HWc] = acc;
        }
    }
}

extern "C" void kernel_launch(void* const* d_in, const int* in_sizes, int n_in,
                              void* d_out, int out_size, void* d_ws, size_t ws_size,
                              hipStream_t stream) {
    const float* x = (const float*)d_in[0];
    const float* sw = (const float*)d_in[1];
    float* out = (float*)d_out;
    cooc_kernel<<<dim3(NTX * NTX, 8), dim3(256), 0, stream>>>(x, sw, out);
}

// Round 6
// 61.913 us; speedup vs baseline: 4.7442x; 1.4026x over previous
//
#include <hip/hip_runtime.h>

// CoOccurrence via MFMA: per 8x8 pixel tile (12x12=144 halo), both phases are
// matmuls over fp16-staged LDS:
//   GEMM1: D[q,p] = sum_ch x[ch,q]*x[ch,p]   (Ht^T * C, 16x16x32_f16, band-restricted)
//   epi1 : W[p,q] = ((D/max(|x_p||x_q|,eps))+1)*0.5*sw[q-p]  (0 outside 5x5 band)
//   GEMM2: out[ch,p] = sum_q x[ch,q]*W[p,q]  (k-band restricted)
// Zero-padded halo => OOB taps: dot=0, nx=0 -> sim=0/eps=0, tap=0 -> contribution
// exactly 0 (matches reference zero-pad semantics).
// Single LDS layout Hs[ch][SH=170] fp16: stride 170 makes strided-u16 fragment
// reads <=2-way bank conflicts (85 mod 32 = 21 coprime; +8 rows -> +32B -> +8 banks).

typedef _Float16 half8 __attribute__((ext_vector_type(8)));
typedef _Float16 half2t __attribute__((ext_vector_type(2)));
typedef float f32x4 __attribute__((ext_vector_type(4)));

constexpr int Cc = 64, Hc = 112, Wc = 112;
constexpr int HWc = Hc * Wc;
constexpr float EPSc = 1e-8f;
constexpr int TH = 8, TW = 8;
constexpr int WR = 12, HALO = 144;   // 12x12 halo
constexpr int SH = 170;              // fp16 row stride for Hs/Wt
constexpr int NTX = 14;              // 112/8

__global__ __launch_bounds__(256, 3) void cooc_mfma(
    const float* __restrict__ x, const float* __restrict__ swg,
    float* __restrict__ out)
{
    __shared__ __align__(16) _Float16 Hs[64 * SH];  // x tile, [ch][halo pos]
    __shared__ __align__(16) _Float16 Wt[64 * SH];  // weights, [center p][halo q]
    __shared__ float nxs[HALO];                     // ||x|| per halo pos
    __shared__ int   goffs[HALO];                   // global offset per halo pos (-1 OOB)
    __shared__ float sws[25];

    const int t = threadIdx.x;
    const int wv = t >> 6, l = t & 63;
    const int lo16 = l & 15, hi4 = l >> 4;
    const int b = blockIdx.y;
    const int th = blockIdx.x / NTX, twi = blockIdx.x - th * NTX;
    const int h0 = th * TH, w0 = twi * TW;
    const float* xb = x + (size_t)b * Cc * HWc;

    // ---- phase 0: tables + zero-init both LDS arrays ----
    if (t < HALO) {
        const int r_ = t / 12, c_ = t - r_ * 12;
        const int gh = h0 + r_ - 2, gw = w0 + c_ - 2;
        const bool v = ((unsigned)gh < (unsigned)Hc) && ((unsigned)gw < (unsigned)Wc);
        goffs[t] = v ? (gh * Wc + gw) : -1;
    }
    if (t < 25) sws[t] = swg[t];
    {
        uint* hz = (uint*)Hs;
        uint* wz = (uint*)Wt;
#pragma unroll
        for (int i = 0; i < (64 * SH / 2 + 255) / 256; ++i) {
            const int idx = t + i * 256;
            if (idx < 64 * SH / 2) { hz[idx] = 0u; wz[idx] = 0u; }
        }
    }
    __syncthreads();

    // ---- phase 1: stage x -> fp16 Hs (coalesced: lanes run along halo pos) ----
    {
        int ch_ = (t >= HALO) ? 1 : 0;
        int pos_ = t - ch_ * HALO;
#pragma unroll
        for (int it = 0; it < 36; ++it) {          // 36*256 = 64*144
            const int go = goffs[pos_];
            const float v = (go >= 0) ? xb[(size_t)ch_ * HWc + go] : 0.f;
            Hs[ch_ * SH + pos_] = (_Float16)v;
            pos_ += 112; ch_ += 1;
            if (pos_ >= HALO) { pos_ -= HALO; ch_ += 1; }
        }
    }
    __syncthreads();

    // ---- phase 1b: nxs[pos] = sqrt(sum_ch x^2) from staged fp16 ----
    if (t < HALO) {
        float s = 0.f;
#pragma unroll 16
        for (int c = 0; c < 64; ++c) {
            const float v = (float)Hs[c * SH + t];
            s = fmaf(v, v, s);
        }
        nxs[t] = sqrtf(s);
    }
    __syncthreads();

    // ---- GEMM1: D = H^T * C, wave wv owns n-tile wv (centers 16wv..16wv+15),
    //      m-tiles band-restricted to 5 starting at mt_lo ----
    const int p = wv * 16 + lo16;                        // this lane's center (B n-index)
    const int cpos = ((p >> 3) + 2) * WR + (p & 7) + 2;  // center's halo position
    half8 bfr[2];
#pragma unroll
    for (int ks = 0; ks < 2; ++ks)
#pragma unroll
        for (int j = 0; j < 8; ++j)
            bfr[ks][j] = Hs[(ks * 32 + hi4 * 8 + j) * SH + cpos];

    const int mt_lo = (3 * wv) >> 1;                     // 0,1,3,4
    f32x4 acc[5];
#pragma unroll
    for (int i = 0; i < 5; ++i) acc[i] = (f32x4){0.f, 0.f, 0.f, 0.f};
#pragma unroll
    for (int i = 0; i < 5; ++i) {
        const int q0 = (mt_lo + i) * 16 + lo16;          // A m-index (halo q)
#pragma unroll
        for (int ks = 0; ks < 2; ++ks) {
            half8 afr;
#pragma unroll
            for (int j = 0; j < 8; ++j)
                afr[j] = Hs[(ks * 32 + hi4 * 8 + j) * SH + q0];
            acc[i] = __builtin_amdgcn_mfma_f32_16x16x32_f16(afr, bfr[ks], acc[i], 0, 0, 0);
        }
    }

    // ---- epi1: dots -> fp16 weights into Wt[p][q] ----
    {
        const float nxp = nxs[cpos];
        const int prw = p >> 3, pcl = p & 7;
#pragma unroll
        for (int i = 0; i < 5; ++i) {
            const int qb = (mt_lo + i) * 16 + hi4 * 4;   // 4 consecutive q (D rows)
            _Float16 hw[4];
#pragma unroll
            for (int r = 0; r < 4; ++r) {
                const int q = qb + r;
                const int qr = q / 12, qc = q - qr * 12;
                const int ih = qr - prw, iw = qc - pcl;  // in band iff both in [0,4]
                const float sv = ((unsigned)ih <= 4u && (unsigned)iw <= 4u)
                                     ? sws[ih * 5 + iw] : 0.f;
                const float denom = fmaxf(nxp * nxs[q], EPSc);
                const float sim = acc[i][r] / denom;
                hw[r] = (_Float16)((sim + 1.f) * 0.5f * sv);
            }
            half2t w0p = {hw[0], hw[1]}, w1p = {hw[2], hw[3]};
            uint* dst = (uint*)&Wt[p * SH + qb];         // qb*2 % 8 == 0, row*340 % 4 == 0
            dst[0] = __builtin_bit_cast(uint, w0p);
            dst[1] = __builtin_bit_cast(uint, w1p);
        }
    }
    __syncthreads();

    // ---- GEMM2: Out = Hs * W^T: wave wv owns m-tile wv (ch 16wv..16wv+15),
    //      K band-restricted to 3 k-steps per n-tile ----
    const int arow = wv * 16 + lo16;                     // ch (A m-index)
    half8 a2[5];
#pragma unroll
    for (int ks = 0; ks < 5; ++ks) {
        const uint* src = (const uint*)&Hs[arow * SH + ks * 32 + hi4 * 8];
#pragma unroll
        for (int jj = 0; jj < 4; ++jj) {
            const half2t h2 = __builtin_bit_cast(half2t, src[jj]);
            a2[ks][2 * jj] = h2[0]; a2[ks][2 * jj + 1] = h2[1];
        }
    }
    f32x4 acc2[4];
#pragma unroll
    for (int nt = 0; nt < 4; ++nt) acc2[nt] = (f32x4){0.f, 0.f, 0.f, 0.f};
#pragma unroll
    for (int nt = 0; nt < 4; ++nt) {
        const int ksl = (3 * nt) >> 2;                   // 0,0,1,2
        const int nrow = nt * 16 + lo16;                 // center (B n-index) -> Wt row
#pragma unroll
        for (int s = 0; s < 3; ++s) {
            const int ks = ksl + s;
            half8 bfr2;
            const uint* src = (const uint*)&Wt[nrow * SH + ks * 32 + hi4 * 8];
#pragma unroll
            for (int jj = 0; jj < 4; ++jj) {
                const half2t h2 = __builtin_bit_cast(half2t, src[jj]);
                bfr2[2 * jj] = h2[0]; bfr2[2 * jj + 1] = h2[1];
            }
            acc2[nt] = __builtin_amdgcn_mfma_f32_16x16x32_f16(a2[ks], bfr2, acc2[nt], 0, 0, 0);
        }
    }

    // ---- epi2: store D2[ch, center] ----
    float* ob = out + (size_t)b * Cc * HWc;
#pragma unroll
    for (int nt = 0; nt < 4; ++nt) {
        const int c = nt * 16 + lo16;                    // center
        const int gh = h0 + (c >> 3), gw = w0 + (c & 7);
        float* o0 = ob + (size_t)(wv * 16 + hi4 * 4) * HWc + gh * Wc + gw;
#pragma unroll
        for (int r = 0; r < 4; ++r)
            o0[(size_t)r * HWc] = acc2[nt][r];
    }
}

extern "C" void kernel_launch(void* const* d_in, const int* in_sizes, int n_in,
                              void* d_out, int out_size, void* d_ws, size_t ws_size,
                              hipStream_t stream) {
    const float* x = (const float*)d_in[0];
    const float* sw = (const float*)d_in[1];
    float* out = (float*)d_out;
    cooc_mfma<<<dim3(NTX * NTX, 8), dim3(256), 0, stream>>>(x, sw, out);
}

// Round 7
// 47.865 us; speedup vs baseline: 6.1365x; 1.2935x over previous
//
#include <hip/hip_runtime.h>

// CoOccurrence via MFMA, R7: dual-layout fp16 LDS so every fragment load is
// one ds_read_b128.
//   Hs_t[pos][ST_T=72]  : x^T tile, k=channel contiguous  (GEMM1 A/B, norms)
//   Hs2 [ch ][ST_2=160] : x tile, k=pos contiguous, XOR-swizzled (GEMM2 A)
//   Wt  [p  ][ST_W=96]  : weights, per-n-tile 96-col k-window, XOR-swizzled
// GEMM1: D[q,p] = sum_ch x[ch,q] x[ch,p]   (band-restricted m-tiles, as R6)
// epi1 : W[p,q] = ((D/max(|x_p||x_q|,eps))+1)/2 * sw  (0 outside 5x5 band)
// GEMM2: out[ch,p] = sum_q x[ch,q] W[p,q]  (k-band windows 0,0,32,64)
// Zero-padded halo: OOB taps have x=0 -> contribution exactly 0 (reference
// zero-pad semantics). Staging is pos-major: one bounds check per task covers
// 4 channels (same spatial location).

typedef _Float16 half8 __attribute__((ext_vector_type(8)));
typedef _Float16 half4 __attribute__((ext_vector_type(4)));
typedef float f32x4 __attribute__((ext_vector_type(4)));

constexpr int Cc = 64, Hc = 112, Wc = 112;
constexpr int HWc = Hc * Wc;
constexpr float EPSc = 1e-8f;
constexpr int TH = 8, TW = 8;
constexpr int WR = 12, HALO = 144;   // 12x12 halo
constexpr int ST_T = 72;             // Hs_t row stride (fp16), 144B, 16B-mult
constexpr int ST_2 = 160;            // Hs2 row stride, 320B
constexpr int ST_W = 96;             // Wt row stride, 192B
constexpr int NTX = 14;              // 112/8

__device__ __forceinline__ int idx2(int row, int col) {   // Hs2 swizzle
    return (row * ST_2 + col) ^ ((row & 7) << 3);
}
__device__ __forceinline__ int idxw(int row, int col) {   // Wt swizzle
    return (row * ST_W + col) ^ ((row & 7) << 3);
}

__global__ __launch_bounds__(256, 2) void cooc_mfma(
    const float* __restrict__ x, const float* __restrict__ swg,
    float* __restrict__ out)
{
    __shared__ __align__(16) _Float16 Hs_t[HALO * ST_T];  // 20736 B
    __shared__ __align__(16) _Float16 Hs2[64 * ST_2];     // 20480 B
    __shared__ __align__(16) _Float16 Wt[64 * ST_W];      // 12288 B
    __shared__ float nxs[HALO];
    __shared__ float sws[25];

    const int t = threadIdx.x;
    const int wv = t >> 6, l = t & 63;
    const int lo16 = l & 15, hi4 = l >> 4;
    const int b = blockIdx.y;
    const int th = blockIdx.x / NTX, twi = blockIdx.x - th * NTX;
    const int h0 = th * TH, w0 = twi * TW;
    const float* xb = x + (size_t)b * Cc * HWc;

    // ---- phase 0: zero-init Wt (all) + Hs2 tail cols [144,160); load sws ----
    {
        const half8 z8 = {0, 0, 0, 0, 0, 0, 0, 0};
#pragma unroll
        for (int i = 0; i < 3; ++i)
            *(half8*)&Wt[(t + i * 256) * 8] = z8;               // 768 ops total
        if (t < 128) {
            const int row = t >> 1, c8 = 144 + (t & 1) * 8;
            *(half8*)&Hs2[idx2(row, c8)] = z8;
        }
        if (t < 25) sws[t] = swg[t];
    }

    // ---- phase 1: stage. task=(pos, 4-ch group); 2304 tasks = 9*256 ----
#pragma unroll
    for (int it = 0; it < 9; ++it) {
        const int task = t + it * 256;
        const int cq = task / HALO;
        const int pos = task - cq * HALO;
        const int r_ = pos / WR, c_ = pos - r_ * WR;
        const int gh = h0 + r_ - 2, gw = w0 + c_ - 2;
        const bool inb = ((unsigned)gh < (unsigned)Hc) && ((unsigned)gw < (unsigned)Wc);
        const float* src = xb + (size_t)(cq * 4) * HWc + gh * Wc + gw;
        float v0 = 0.f, v1 = 0.f, v2 = 0.f, v3 = 0.f;
        if (inb) {
            v0 = src[0];
            v1 = src[(size_t)1 * HWc];
            v2 = src[(size_t)2 * HWc];
            v3 = src[(size_t)3 * HWc];
        }
        const _Float16 h0v = (_Float16)v0, h1v = (_Float16)v1;
        const _Float16 h2v = (_Float16)v2, h3v = (_Float16)v3;
        const int ch0 = cq * 4;
        half4 hv = {h0v, h1v, h2v, h3v};
        *(half4*)&Hs_t[pos * ST_T + ch0] = hv;   // b64, 8B aligned
        Hs2[idx2(ch0 + 0, pos)] = h0v;
        Hs2[idx2(ch0 + 1, pos)] = h1v;
        Hs2[idx2(ch0 + 2, pos)] = h2v;
        Hs2[idx2(ch0 + 3, pos)] = h3v;
    }
    __syncthreads();

    // ---- phase 1b: nxs[pos] = ||x(pos)|| from Hs_t row (8x b128) ----
    if (t < HALO) {
        float s = 0.f;
        const half8* row = (const half8*)&Hs_t[t * ST_T];
#pragma unroll
        for (int i = 0; i < 8; ++i) {
            const half8 h = row[i];
#pragma unroll
            for (int j = 0; j < 8; ++j) {
                const float f = (float)h[j];
                s = fmaf(f, f, s);
            }
        }
        nxs[t] = sqrtf(s);
    }

    // ---- GEMM1: D = H^T*C, wave wv owns centers p=wv*16+lo16 (n), 5 m-tiles ----
    const int p = wv * 16 + lo16;
    const int cpos = ((p >> 3) + 2) * WR + (p & 7) + 2;
    half8 bfr[2];
#pragma unroll
    for (int ks = 0; ks < 2; ++ks)
        bfr[ks] = *(const half8*)&Hs_t[cpos * ST_T + ks * 32 + hi4 * 8];

    const int mt_lo = (3 * wv) >> 1;                 // 0,1,3,4
    f32x4 acc[5];
#pragma unroll
    for (int i = 0; i < 5; ++i) acc[i] = (f32x4){0.f, 0.f, 0.f, 0.f};
#pragma unroll
    for (int i = 0; i < 5; ++i) {
        const int q0 = (mt_lo + i) * 16 + lo16;
#pragma unroll
        for (int ks = 0; ks < 2; ++ks) {
            const half8 afr = *(const half8*)&Hs_t[q0 * ST_T + ks * 32 + hi4 * 8];
            acc[i] = __builtin_amdgcn_mfma_f32_16x16x32_f16(afr, bfr[ks], acc[i], 0, 0, 0);
        }
    }
    __syncthreads();   // nxs visible to all; Hs_t reads done

    // ---- GEMM2 A-frags early (hide under epi1) ----
    const int arow = wv * 16 + lo16;                 // channel (m)
    half8 a2[5];
#pragma unroll
    for (int ks = 0; ks < 5; ++ks)
        a2[ks] = *(const half8*)&Hs2[idx2(arow, ks * 32 + hi4 * 8)];

    // ---- epi1: dots -> fp16 weights into Wt (band window W0 = ksl(wv)*32) ----
    {
        const float nxp = nxs[cpos];
        const int W0 = ((3 * wv) >> 2) * 32;         // 0,0,32,64
        const int prw = p >> 3, pcl = p & 7;
#pragma unroll
        for (int i = 0; i < 5; ++i) {
            const int qb = (mt_lo + i) * 16 + hi4 * 4;
            _Float16 hw[4];
#pragma unroll
            for (int r = 0; r < 4; ++r) {
                const int q = qb + r;
                const int qr = q / WR, qc = q - qr * WR;
                const int ih = qr - prw, iw = qc - pcl;
                const float sv = ((unsigned)ih <= 4u && (unsigned)iw <= 4u)
                                     ? sws[ih * 5 + iw] : 0.f;
                const float denom = fmaxf(nxp * nxs[q], EPSc);
                const float sim = acc[i][r] / denom;
                hw[r] = (_Float16)((sim + 1.f) * 0.5f * sv);
            }
            half4 w4 = {hw[0], hw[1], hw[2], hw[3]};
            *(half4*)&Wt[idxw(p, qb - W0)] = w4;     // 8B aligned (qb-W0 mult 4)
        }
    }
    __syncthreads();   // Wt complete

    // ---- GEMM2: Out = Hs * W^T, wave wv owns ch m-tile wv; 3 k-steps/n-tile ----
    f32x4 acc2[4];
#pragma unroll
    for (int nt = 0; nt < 4; ++nt) acc2[nt] = (f32x4){0.f, 0.f, 0.f, 0.f};
#pragma unroll
    for (int nt = 0; nt < 4; ++nt) {
        const int ksl = (3 * nt) >> 2;               // 0,0,1,2
        const int nrow = nt * 16 + lo16;             // center (n)
#pragma unroll
        for (int s = 0; s < 3; ++s) {
            const half8 bfr2 = *(const half8*)&Wt[idxw(nrow, s * 32 + hi4 * 8)];
            acc2[nt] = __builtin_amdgcn_mfma_f32_16x16x32_f16(a2[ksl + s], bfr2, acc2[nt], 0, 0, 0);
        }
    }

    // ---- epi2: store out[ch, center] ----
    float* ob = out + (size_t)b * Cc * HWc;
#pragma unroll
    for (int nt = 0; nt < 4; ++nt) {
        const int c = nt * 16 + lo16;
        const int gh = h0 + (c >> 3), gw = w0 + (c & 7);
        float* o0 = ob + (size_t)(wv * 16 + hi4 * 4) * HWc + gh * Wc + gw;
#pragma unroll
        for (int r = 0; r < 4; ++r)
            o0[(size_t)r * HWc] = acc2[nt][r];
    }
}

extern "C" void kernel_launch(void* const* d_in, const int* in_sizes, int n_in,
                              void* d_out, int out_size, void* d_ws, size_t ws_size,
                              hipStream_t stream) {
    const float* x = (const float*)d_in[0];
    const float* sw = (const float*)d_in[1];
    float* out = (float*)d_out;
    cooc_mfma<<<dim3(NTX * NTX, 8), dim3(256), 0, stream>>>(x, sw, out);
}

// Round 8
// 45.576 us; speedup vs baseline: 6.4447x; 1.0502x over previous
//
#include <hip/hip_runtime.h>

// CoOccurrence via MFMA, R8: R7 dual-layout structure with
//  (1) Wt aliased onto Hs_t (dead after GEMM1 frag reads) -> 41.9 KB LDS,
//      3 blocks/CU at launch_bounds(256,3)
//  (2) float2 staging (pairs never cross rows/W-edge; 1 bounds check / 8 vals)
//  (3) GEMM2 operand-swap: out[p][ch] accumulator -> epi2 = 4 float4 stores.
// Layouts:
//   Hs_t[pos][ST_T=72]  fp16, k=channel contiguous  (GEMM1 A/B, norms)
//   Hs2 [ch ][ST_2=160] fp16, k=pos contiguous, XOR-swizzled (GEMM2 B)
//   Wt  [p  ][ST_W=96]  fp16, per-tile 96-col k-window, XOR-swizzled (GEMM2 A)
// GEMM1: D[q,p] = sum_ch x[ch,q] x[ch,p]  (band-restricted m-tiles)
// epi1 : W[p,q] = ((D/max(|x_p||x_q|,eps))+1)/2 * sw  (0 outside 5x5 band)
// GEMM2: out[p,ch] = sum_q W[p,q] x[ch,q]  (k-windows 0,0,32,64)
// Zero-padded halo: OOB taps are 0 -> contribution exactly 0 (reference
// zero-pad semantics).

typedef _Float16 half8 __attribute__((ext_vector_type(8)));
typedef _Float16 half4 __attribute__((ext_vector_type(4)));
typedef _Float16 half2t __attribute__((ext_vector_type(2)));
typedef float f32x4 __attribute__((ext_vector_type(4)));
typedef float f32x2 __attribute__((ext_vector_type(2)));

constexpr int Cc = 64, Hc = 112, Wc = 112;
constexpr int HWc = Hc * Wc;
constexpr float EPSc = 1e-8f;
constexpr int TH = 8, TW = 8;
constexpr int WR = 12, HALO = 144;   // 12x12 halo
constexpr int ST_T = 72;             // Hs_t row stride (fp16): 144B, 16B-mult
constexpr int ST_2 = 160;            // Hs2 row stride
constexpr int ST_W = 96;             // Wt row stride
constexpr int NTX = 14;              // 112/8

__device__ __forceinline__ int idx2(int row, int col) {   // Hs2 swizzle
    return (row * ST_2 + col) ^ ((row & 7) << 3);
}
__device__ __forceinline__ int idxw(int row, int col) {   // Wt swizzle
    return (row * ST_W + col) ^ ((row & 7) << 3);
}

__global__ __launch_bounds__(256, 3) void cooc_mfma(
    const float* __restrict__ x, const float* __restrict__ swg,
    float* __restrict__ out)
{
    __shared__ __align__(16) _Float16 Hs_t[HALO * ST_T];  // 20736 B (Wt aliases)
    __shared__ __align__(16) _Float16 Hs2[64 * ST_2];     // 20480 B
    __shared__ float nxs[HALO];
    __shared__ float sws[25];
    _Float16* const Wt = Hs_t;   // alias: Hs_t dead after GEMM1/norm reads

    const int t = threadIdx.x;
    const int wv = t >> 6, l = t & 63;
    const int lo16 = l & 15, hi4 = l >> 4;
    const int b = blockIdx.y;
    const int th = blockIdx.x / NTX, twi = blockIdx.x - th * NTX;
    const int h0 = th * TH, w0 = twi * TW;
    const float* xb = x + (size_t)b * Cc * HWc;
    const half8 z8 = {0, 0, 0, 0, 0, 0, 0, 0};

    // ---- phase 0: zero Hs2 k-tail cols [144,160); load sws ----
    if (t < 128) {
        const int row = t >> 1, c8 = 144 + (t & 1) * 8;
        *(half8*)&Hs2[idx2(row, c8)] = z8;
    }
    if (t < 25) sws[t] = swg[t];

    // ---- phase 1: stage. task=(4-ch group cq, pos-pair pp); 1152 tasks ----
#pragma unroll
    for (int it = 0; it < 5; ++it) {
        const int task = t + it * 256;
        if (task < 1152) {
            const int cq = task / 72;
            const int pp = task - cq * 72;
            const int r_ = pp / 6, pc2 = (pp - r_ * 6) * 2;
            const int gh = h0 + r_ - 2, gw = w0 + pc2 - 2;   // gw always even
            const bool inb = ((unsigned)gh < (unsigned)Hc) && ((unsigned)gw < (unsigned)Wc);
            const int ch0 = cq * 4;
            const float* src = xb + (size_t)ch0 * HWc + gh * Wc + gw;
            f32x2 v0 = {0.f, 0.f}, v1 = v0, v2 = v0, v3 = v0;
            if (inb) {
                v0 = *(const f32x2*)(src);
                v1 = *(const f32x2*)(src + (size_t)1 * HWc);
                v2 = *(const f32x2*)(src + (size_t)2 * HWc);
                v3 = *(const f32x2*)(src + (size_t)3 * HWc);
            }
            const int pos0 = r_ * WR + pc2;
            const half4 hx = {(_Float16)v0.x, (_Float16)v1.x, (_Float16)v2.x, (_Float16)v3.x};
            const half4 hy = {(_Float16)v0.y, (_Float16)v1.y, (_Float16)v2.y, (_Float16)v3.y};
            *(half4*)&Hs_t[pos0 * ST_T + ch0] = hx;
            *(half4*)&Hs_t[(pos0 + 1) * ST_T + ch0] = hy;
            const half2t p0 = {hx[0], hy[0]}, p1 = {hx[1], hy[1]};
            const half2t p2 = {hx[2], hy[2]}, p3 = {hx[3], hy[3]};
            *(half2t*)&Hs2[idx2(ch0 + 0, pos0)] = p0;
            *(half2t*)&Hs2[idx2(ch0 + 1, pos0)] = p1;
            *(half2t*)&Hs2[idx2(ch0 + 2, pos0)] = p2;
            *(half2t*)&Hs2[idx2(ch0 + 3, pos0)] = p3;
        }
    }
    __syncthreads();

    // ---- nxs[pos] = ||x(pos)|| (waves 0-1+; waves 2-3 go straight to GEMM1) ----
    if (t < HALO) {
        float s = 0.f;
        const half8* row = (const half8*)&Hs_t[t * ST_T];
#pragma unroll
        for (int i = 0; i < 8; ++i) {
            const half8 h = row[i];
#pragma unroll
            for (int j = 0; j < 8; ++j) {
                const float f = (float)h[j];
                s = fmaf(f, f, s);
            }
        }
        nxs[t] = sqrtf(s);
    }

    // ---- GEMM1: D = H^T*C; wave wv: centers p (n), 5 band m-tiles ----
    const int p = wv * 16 + lo16;
    const int cpos = ((p >> 3) + 2) * WR + (p & 7) + 2;
    half8 bfr[2];
#pragma unroll
    for (int ks = 0; ks < 2; ++ks)
        bfr[ks] = *(const half8*)&Hs_t[cpos * ST_T + ks * 32 + hi4 * 8];

    const int mt_lo = (3 * wv) >> 1;                 // 0,1,3,4
    f32x4 acc[5];
#pragma unroll
    for (int i = 0; i < 5; ++i) acc[i] = (f32x4){0.f, 0.f, 0.f, 0.f};
#pragma unroll
    for (int i = 0; i < 5; ++i) {
        const int q0 = (mt_lo + i) * 16 + lo16;
#pragma unroll
        for (int ks = 0; ks < 2; ++ks) {
            const half8 afr = *(const half8*)&Hs_t[q0 * ST_T + ks * 32 + hi4 * 8];
            acc[i] = __builtin_amdgcn_mfma_f32_16x16x32_f16(afr, bfr[ks], acc[i], 0, 0, 0);
        }
    }

    // ---- GEMM2 B-frags (Hs2 ready since the barrier; overlap with GEMM1) ----
    half8 b2[5];
#pragma unroll
    for (int ks = 0; ks < 5; ++ks)
        b2[ks] = *(const half8*)&Hs2[idx2(wv * 16 + lo16, ks * 32 + hi4 * 8)];

    __syncthreads();   // Hs_t/norm reads done; nxs visible; Wt(=Hs_t) writable

    // ---- zero Wt's unwritten 16 cols per row, then epi1 ----
    {
        const int zc = (wv == 0 || wv == 3) ? 80 : 0;
        if (hi4 < 2) *(half8*)&Wt[idxw(p, zc + hi4 * 8)] = z8;

        const float nxp = nxs[cpos];
        const int W0 = ((3 * wv) >> 2) * 32;         // 0,0,32,64
        const int prw = p >> 3, pcl = p & 7;
#pragma unroll
        for (int i = 0; i < 5; ++i) {
            const int qb = (mt_lo + i) * 16 + hi4 * 4;
            _Float16 hw[4];
#pragma unroll
            for (int r = 0; r < 4; ++r) {
                const int q = qb + r;
                const int qr = q / WR, qc = q - qr * WR;
                const int ih = qr - prw, iw = qc - pcl;
                const float sv = ((unsigned)ih <= 4u && (unsigned)iw <= 4u)
                                     ? sws[ih * 5 + iw] : 0.f;
                const float denom = fmaxf(nxp * nxs[q], EPSc);
                const float sim = acc[i][r] / denom;
                hw[r] = (_Float16)((sim + 1.f) * 0.5f * sv);
            }
            const half4 w4 = {hw[0], hw[1], hw[2], hw[3]};
            *(half4*)&Wt[idxw(p, qb - W0)] = w4;
        }
    }
    __syncthreads();   // Wt complete

    // ---- GEMM2: out[p,ch] = sum_q W[p,q] x[ch,q]; A=Wt, B=Hs2 frags ----
    f32x4 acc2[4];
#pragma unroll
    for (int nt = 0; nt < 4; ++nt) acc2[nt] = (f32x4){0.f, 0.f, 0.f, 0.f};
#pragma unroll
    for (int nt = 0; nt < 4; ++nt) {
        const int ksl = (3 * nt) >> 2;               // 0,0,1,2
#pragma unroll
        for (int s = 0; s < 3; ++s) {
            const half8 wtf = *(const half8*)&Wt[idxw(nt * 16 + lo16, s * 32 + hi4 * 8)];
            acc2[nt] = __builtin_amdgcn_mfma_f32_16x16x32_f16(wtf, b2[ksl + s], acc2[nt], 0, 0, 0);
        }
    }

    // ---- epi2: lane owns ch = wv*16+lo16; 4 consecutive pixels -> float4 ----
    {
        const int ch = wv * 16 + lo16;
        float* ochan = out + (size_t)b * Cc * HWc + (size_t)ch * HWc;
        const int pr_base = hi4 >> 1, pc0 = (hi4 & 1) * 4;
#pragma unroll
        for (int nt = 0; nt < 4; ++nt) {
            const int gh = h0 + 2 * nt + pr_base;
            *(f32x4*)&ochan[gh * Wc + w0 + pc0] = acc2[nt];
        }
    }
}

extern "C" void kernel_launch(void* const* d_in, const int* in_sizes, int n_in,
                              void* d_out, int out_size, void* d_ws, size_t ws_size,
                              hipStream_t stream) {
    const float* x = (const float*)d_in[0];
    const float* sw = (const float*)d_in[1];
    float* out = (float*)d_out;
    cooc_mfma<<<dim3(NTX * NTX, 8), dim3(256), 0, stream>>>(x, sw, out);
}

// Round 9
// 26.189 us; speedup vs baseline: 11.2155x; 1.7403x over previous
//
#include <hip/hip_runtime.h>

// CoOccurrence via MFMA, R9: R8 structure +
//  (1) Hs_t stride 72->64 with per-row XOR swizzle idxt (bijective, col<64):
//      GEMM1 frag reads go ~8-way -> 2-way bank conflicts; -2.3KB LDS
//  (2) total LDS 39.6KB -> 4 blocks/CU, launch_bounds(256,4)
//  (3) XCD-aware 1D block swizzle: b = bid&7 (one image per XCD), tile =
//      bid>>3 row-major -> neighbor tiles share halo via same-XCD L2.
// Layouts:
//   Hs_t[pos][64]  fp16 XOR-swizzled, k=channel contiguous (GEMM1 A/B, norms)
//   Hs2 [ch ][160] fp16 flat-XOR swizzle (validated R7/R8), k=pos contiguous
//   Wt  [p  ][96]  fp16 (aliases Hs_t), per-quadrant 96-col k-window
// GEMM1: D[q,p] = sum_ch x[ch,q] x[ch,p]  (band-restricted m-tiles)
// epi1 : W[p,q] = ((D/max(|x_p||x_q|,eps))+1)/2 * sw  (0 outside 5x5 band)
// GEMM2: out[p,ch] = sum_q W[p,q] x[ch,q]  (k-windows 0,0,32,64)
// Zero-padded halo: OOB taps are 0 -> contribution exactly 0.

typedef _Float16 half8 __attribute__((ext_vector_type(8)));
typedef _Float16 half4 __attribute__((ext_vector_type(4)));
typedef _Float16 half2t __attribute__((ext_vector_type(2)));
typedef float f32x4 __attribute__((ext_vector_type(4)));
typedef float f32x2 __attribute__((ext_vector_type(2)));

constexpr int Cc = 64, Hc = 112, Wc = 112;
constexpr int HWc = Hc * Wc;
constexpr float EPSc = 1e-8f;
constexpr int TH = 8, TW = 8;
constexpr int WR = 12, HALO = 144;   // 12x12 halo
constexpr int ST_2 = 160;            // Hs2 row stride
constexpr int ST_W = 96;             // Wt row stride
constexpr int NTX = 14;              // 112/8

__device__ __forceinline__ int idxt(int pos, int col) {   // Hs_t swizzle
    return pos * 64 + (col ^ ((pos & 7) << 3));           // bijective: col<64
}
__device__ __forceinline__ int idx2(int row, int col) {   // Hs2 swizzle
    return (row * ST_2 + col) ^ ((row & 7) << 3);
}
__device__ __forceinline__ int idxw(int row, int col) {   // Wt swizzle
    return (row * ST_W + col) ^ ((row & 7) << 3);
}

__global__ __launch_bounds__(256, 4) void cooc_mfma(
    const float* __restrict__ x, const float* __restrict__ swg,
    float* __restrict__ out)
{
    __shared__ __align__(16) _Float16 Hs_t[HALO * 64];    // 18432 B (Wt aliases)
    __shared__ __align__(16) _Float16 Hs2[64 * ST_2];     // 20480 B
    __shared__ float nxs[HALO];
    __shared__ float sws[25];
    _Float16* const Wt = Hs_t;   // alias: Hs_t dead after GEMM1/norm reads

    const int t = threadIdx.x;
    const int wv = t >> 6, l = t & 63;
    const int lo16 = l & 15, hi4 = l >> 4;
    // XCD swizzle: 1568 = 8 XCDs x 196 tiles; b = xcd, tile row-major per XCD.
    const int bid = blockIdx.x;
    const int b = bid & 7;
    const int tile = bid >> 3;
    const int th = tile / NTX, twi = tile - th * NTX;
    const int h0 = th * TH, w0 = twi * TW;
    const float* xb = x + (size_t)b * Cc * HWc;
    const half8 z8 = {0, 0, 0, 0, 0, 0, 0, 0};

    // ---- phase 0: zero Hs2 k-tail cols [144,160); load sws ----
    if (t < 128) {
        const int row = t >> 1, c8 = 144 + (t & 1) * 8;
        *(half8*)&Hs2[idx2(row, c8)] = z8;
    }
    if (t < 25) sws[t] = swg[t];

    // ---- phase 1: stage. task=(4-ch group cq, pos-pair pp); 1152 tasks ----
#pragma unroll
    for (int it = 0; it < 5; ++it) {
        const int task = t + it * 256;
        if (task < 1152) {
            const int cq = task / 72;
            const int pp = task - cq * 72;
            const int r_ = pp / 6, pc2 = (pp - r_ * 6) * 2;
            const int gh = h0 + r_ - 2, gw = w0 + pc2 - 2;   // gw always even
            const bool inb = ((unsigned)gh < (unsigned)Hc) && ((unsigned)gw < (unsigned)Wc);
            const int ch0 = cq * 4;
            const float* src = xb + (size_t)ch0 * HWc + gh * Wc + gw;
            f32x2 v0 = {0.f, 0.f}, v1 = v0, v2 = v0, v3 = v0;
            if (inb) {
                v0 = *(const f32x2*)(src);
                v1 = *(const f32x2*)(src + (size_t)1 * HWc);
                v2 = *(const f32x2*)(src + (size_t)2 * HWc);
                v3 = *(const f32x2*)(src + (size_t)3 * HWc);
            }
            const int pos0 = r_ * WR + pc2;
            const half4 hx = {(_Float16)v0.x, (_Float16)v1.x, (_Float16)v2.x, (_Float16)v3.x};
            const half4 hy = {(_Float16)v0.y, (_Float16)v1.y, (_Float16)v2.y, (_Float16)v3.y};
            *(half4*)&Hs_t[idxt(pos0, ch0)] = hx;       // ch0^mask stays mult-4
            *(half4*)&Hs_t[idxt(pos0 + 1, ch0)] = hy;
            const half2t p0 = {hx[0], hy[0]}, p1 = {hx[1], hy[1]};
            const half2t p2 = {hx[2], hy[2]}, p3 = {hx[3], hy[3]};
            *(half2t*)&Hs2[idx2(ch0 + 0, pos0)] = p0;
            *(half2t*)&Hs2[idx2(ch0 + 1, pos0)] = p1;
            *(half2t*)&Hs2[idx2(ch0 + 2, pos0)] = p2;
            *(half2t*)&Hs2[idx2(ch0 + 3, pos0)] = p3;
        }
    }
    __syncthreads();

    // ---- nxs[pos] = ||x(pos)|| (threads 0-143; waves 2-3 run ahead) ----
    if (t < HALO) {
        float s = 0.f;
#pragma unroll
        for (int i = 0; i < 8; ++i) {
            const half8 h = *(const half8*)&Hs_t[idxt(t, i * 8)];
#pragma unroll
            for (int j = 0; j < 8; ++j) {
                const float f = (float)h[j];
                s = fmaf(f, f, s);
            }
        }
        nxs[t] = sqrtf(s);
    }

    // ---- GEMM1: D = H^T*C; wave wv: centers p (n), 5 band m-tiles ----
    const int p = wv * 16 + lo16;
    const int cpos = ((p >> 3) + 2) * WR + (p & 7) + 2;
    half8 bfr[2];
#pragma unroll
    for (int ks = 0; ks < 2; ++ks)
        bfr[ks] = *(const half8*)&Hs_t[idxt(cpos, ks * 32 + hi4 * 8)];

    const int mt_lo = (3 * wv) >> 1;                 // 0,1,3,4
    f32x4 acc[5];
#pragma unroll
    for (int i = 0; i < 5; ++i) acc[i] = (f32x4){0.f, 0.f, 0.f, 0.f};
#pragma unroll
    for (int i = 0; i < 5; ++i) {
        const int q0 = (mt_lo + i) * 16 + lo16;
#pragma unroll
        for (int ks = 0; ks < 2; ++ks) {
            const half8 afr = *(const half8*)&Hs_t[idxt(q0, ks * 32 + hi4 * 8)];
            acc[i] = __builtin_amdgcn_mfma_f32_16x16x32_f16(afr, bfr[ks], acc[i], 0, 0, 0);
        }
    }

    // ---- GEMM2 B-frags (Hs2 ready since barrier; overlap with GEMM1) ----
    half8 b2[5];
#pragma unroll
    for (int ks = 0; ks < 5; ++ks)
        b2[ks] = *(const half8*)&Hs2[idx2(wv * 16 + lo16, ks * 32 + hi4 * 8)];

    __syncthreads();   // Hs_t/norm reads done; nxs visible; Wt(=Hs_t) writable

    // ---- zero Wt's unwritten 16 cols per row, then epi1 ----
    {
        const int zc = (wv == 0 || wv == 3) ? 80 : 0;
        if (hi4 < 2) *(half8*)&Wt[idxw(p, zc + hi4 * 8)] = z8;

        const float nxp = nxs[cpos];
        const int W0 = ((3 * wv) >> 2) * 32;         // 0,0,32,64
        const int prw = p >> 3, pcl = p & 7;
#pragma unroll
        for (int i = 0; i < 5; ++i) {
            const int qb = (mt_lo + i) * 16 + hi4 * 4;
            _Float16 hw[4];
#pragma unroll
            for (int r = 0; r < 4; ++r) {
                const int q = qb + r;
                const int qr = q / WR, qc = q - qr * WR;
                const int ih = qr - prw, iw = qc - pcl;
                const float sv = ((unsigned)ih <= 4u && (unsigned)iw <= 4u)
                                     ? sws[ih * 5 + iw] : 0.f;
                const float denom = fmaxf(nxp * nxs[q], EPSc);
                const float sim = acc[i][r] / denom;
                hw[r] = (_Float16)((sim + 1.f) * 0.5f * sv);
            }
            const half4 w4 = {hw[0], hw[1], hw[2], hw[3]};
            *(half4*)&Wt[idxw(p, qb - W0)] = w4;
        }
    }
    __syncthreads();   // Wt complete

    // ---- GEMM2: out[p,ch] = sum_q W[p,q] x[ch,q]; A=Wt, B=Hs2 frags ----
    f32x4 acc2[4];
#pragma unroll
    for (int nt = 0; nt < 4; ++nt) acc2[nt] = (f32x4){0.f, 0.f, 0.f, 0.f};
#pragma unroll
    for (int nt = 0; nt < 4; ++nt) {
        const int ksl = (3 * nt) >> 2;               // 0,0,1,2
#pragma unroll
        for (int s = 0; s < 3; ++s) {
            const half8 wtf = *(const half8*)&Wt[idxw(nt * 16 + lo16, s * 32 + hi4 * 8)];
            acc2[nt] = __builtin_amdgcn_mfma_f32_16x16x32_f16(wtf, b2[ksl + s], acc2[nt], 0, 0, 0);
        }
    }

    // ---- epi2: lane owns ch = wv*16+lo16; 4 consecutive pixels -> float4 ----
    {
        const int ch = wv * 16 + lo16;
        float* ochan = out + (size_t)b * Cc * HWc + (size_t)ch * HWc;
        const int pr_base = hi4 >> 1, pc0 = (hi4 & 1) * 4;
#pragma unroll
        for (int nt = 0; nt < 4; ++nt) {
            const int gh = h0 + 2 * nt + pr_base;
            *(f32x4*)&ochan[gh * Wc + w0 + pc0] = acc2[nt];
        }
    }
}

extern "C" void kernel_launch(void* const* d_in, const int* in_sizes, int n_in,
                              void* d_out, int out_size, void* d_ws, size_t ws_size,
                              hipStream_t stream) {
    const float* x = (const float*)d_in[0];
    const float* sw = (const float*)d_in[1];
    float* out = (float*)d_out;
    cooc_mfma<<<dim3(8 * NTX * NTX), dim3(256), 0, stream>>>(x, sw, out);
}